// Round 1
// 231.730 us; speedup vs baseline: 1.0049x; 1.0049x over previous
//
#include <hip/hip_runtime.h>
#include <stdint.h>
#include <stddef.h>

#define M_DIM 2048
#define N_DIM 4096
#define K_DIM 4352
#define H_DIM 1024
#define X_DIM 2304

// workspace layout (bytes)
#define A_OFF 0u
#define B_OFF 17825792u                 // 2048*4352*2

typedef __bf16 bf16x8 __attribute__((ext_vector_type(8)));
typedef float f32x4 __attribute__((ext_vector_type(4)));

__device__ __forceinline__ unsigned short f32_to_bf16(float f) {
    unsigned u = __float_as_uint(f);
    u += 0x7FFFu + ((u >> 16) & 1u);     // round-to-nearest-even
    return (unsigned short)(u >> 16);
}

__device__ __forceinline__ float sigm_(float x) { return 1.f / (1.f + __expf(-x)); }
__device__ __forceinline__ float tanh_(float x) {
    x = fminf(15.f, fmaxf(-15.f, x));
    float e = __expf(2.f * x);
    return (e - 1.f) / (e + 1.f);
}

// ---------------------------------------------------------------------------
// Kernel 1 (unchanged): pack z -> A, W_all gate-interleaved -> B. bf16.
// ---------------------------------------------------------------------------
__global__ __launch_bounds__(256) void convert_kernel(
    const float* __restrict__ x, const float* __restrict__ pt,
    const float* __restrict__ pl,
    const float* __restrict__ Wi, const float* __restrict__ Wf,
    const float* __restrict__ Wo, const float* __restrict__ Ws,
    unsigned short* __restrict__ Abf, unsigned short* __restrict__ Bbf)
{
    const int row = blockIdx.x;                  // 0..6143
    const float* srow = nullptr;
    unsigned short* drow;
    if (row < M_DIM) {
        drow = Abf + (size_t)row * K_DIM;
    } else {
        int n = row - M_DIM;                      // 0..4095
        int g = n >> 10, h = n & 1023;
        const float* W = (g == 0) ? Wi : (g == 1) ? Wf : (g == 2) ? Wo : Ws;
        srow = W + (size_t)h * K_DIM;
        drow = Bbf + (size_t)(h * 4 + g) * K_DIM;
    }

    for (int c8 = threadIdx.x; c8 < K_DIM / 8; c8 += 256) {
        int col = c8 * 8;
        const float* s;
        if (row < M_DIM) {
            if (col < X_DIM)              s = x  + (size_t)row * X_DIM + col;
            else if (col < X_DIM + H_DIM) s = pt + (size_t)row * H_DIM + (col - X_DIM);
            else                          s = pl + (size_t)row * H_DIM + (col - X_DIM - H_DIM);
        } else {
            s = srow + col;
        }
        float4 v0 = ((const float4*)s)[0];
        float4 v1 = ((const float4*)s)[1];
        union { unsigned short h[8]; uint4 u; } r;
        r.h[0] = f32_to_bf16(v0.x); r.h[1] = f32_to_bf16(v0.y);
        r.h[2] = f32_to_bf16(v0.z); r.h[3] = f32_to_bf16(v0.w);
        r.h[4] = f32_to_bf16(v1.x); r.h[5] = f32_to_bf16(v1.y);
        r.h[6] = f32_to_bf16(v1.z); r.h[7] = f32_to_bf16(v1.w);
        *(uint4*)(drow + col) = r.u;
    }
}

// ---------------------------------------------------------------------------
// Kernel 2: fused GEMM + gates. NEW: counted-vmcnt phase schedule (T3+T4+T5).
// BM=128, BN=256, BK-half=32, 8 waves (512 thr), wave tile 64x64, 4x4 MFMA
// 16x16x32. Grid 256 blocks = 1/CU. LDS: ring of 4 half-buffers
// (A 8KB + B 16KB = 24KB each, 96KB total), XOR-swizzled k-slots.
// Per phase: 8 ds_read_b128 || 3 global_load_lds (half h+3) -> barrier ->
// lgkmcnt(0) -> setprio(1) 16 MFMA setprio(0) -> vmcnt(6) -> barrier.
// vmcnt never drains to 0 in the main loop: 2 half-tiles stay in flight.
// ---------------------------------------------------------------------------
__global__ __launch_bounds__(512, 2) void gemm_fused(
    const unsigned short* __restrict__ A,   // [M_DIM, K_DIM] bf16
    const unsigned short* __restrict__ B,   // [N_DIM, K_DIM] bf16, gate-interleaved
    const float* __restrict__ old_state,    // [2048, 1024]
    const float* __restrict__ bi, const float* __restrict__ bfv,
    const float* __restrict__ bo, const float* __restrict__ bs,
    float* __restrict__ out)                // [2048, 1024]
{
    // 4 half-buffers at c*24576: A half [128 rows][4 slots of 16B] = 8192 B,
    // B half [256 rows][4 slots] = 16384 B. sP (128*76*4 = 38912 B) aliases
    // buffers 0..1 in the epilogue.
    __shared__ __align__(16) char smem[98304];
    float* sP = (float*)smem;

    const int tid  = threadIdx.x;
    const int lane = tid & 63;
    const int wave = tid >> 6;              // 0..7
    const int wm = (wave >> 2) * 64;        // 0 | 64
    const int wn = (wave & 3) * 64;         // 0 | 64 | 128 | 192

    // XCD-aware decode: xcd owns 2 n-tiles (B panel ~4.5MB ~ L2)
    const int b   = blockIdx.x;             // 0..255
    const int xcd = b & 7;
    const int j   = b >> 3;                 // 0..31
    const int m0  = (j >> 1) * 128;         // 16 m-tiles
    const int n0  = (xcd * 2 + (j & 1)) * 256;  // 16 n-tiles

    // staging: linear LDS slot u*16 (u = i*512 + tid); row = u>>2, slot = u&3,
    // pre-swizzled source k-block kb = slot ^ ((row>>1)&3)
    const int srow_ = tid >> 2;             // 0..127
    const int kb_   = (tid & 3) ^ ((tid >> 3) & 3);
    const unsigned short* Asrc  = A + (size_t)(m0 + srow_)       * K_DIM + kb_ * 8;
    const unsigned short* Bsrc0 = B + (size_t)(n0 + srow_)       * K_DIM + kb_ * 8;
    const unsigned short* Bsrc1 = B + (size_t)(n0 + 128 + srow_) * K_DIM + kb_ * 8;

    // fragment reads: row = w? + i*16 + fr, k-block kb0 = lane>>4,
    // swizzled slot = kb0 ^ ((row>>1)&3) = kb0 ^ ((fr>>1)&3)
    const int fr  = lane & 15;
    const int kb0 = lane >> 4;
    const int swz = (kb0 ^ ((fr >> 1) & 3)) * 16;
    const int aoff = (wm + fr) * 64 + swz;
    const int boff = 8192 + (wn + fr) * 64 + swz;

    f32x4 acc[4][4];
#pragma unroll
    for (int i = 0; i < 4; ++i)
#pragma unroll
        for (int jj = 0; jj < 4; ++jj) acc[i][jj] = (f32x4){0.f, 0.f, 0.f, 0.f};

    // stage half-tile h (k in [h*32, h*32+32)) into ring buffer c: 3 loads/thread
    auto stage = [&](int h, int c) {
        const size_t koff = (size_t)h * 32;
        __builtin_amdgcn_global_load_lds(
            (const __attribute__((address_space(1))) unsigned*)(Asrc + koff),
            (__attribute__((address_space(3))) unsigned*)(smem + c * 24576 + wave * 1024),
            16, 0, 0);
        __builtin_amdgcn_global_load_lds(
            (const __attribute__((address_space(1))) unsigned*)(Bsrc0 + koff),
            (__attribute__((address_space(3))) unsigned*)(smem + c * 24576 + 8192 + wave * 1024),
            16, 0, 0);
        __builtin_amdgcn_global_load_lds(
            (const __attribute__((address_space(1))) unsigned*)(Bsrc1 + koff),
            (__attribute__((address_space(3))) unsigned*)(smem + c * 24576 + 16384 + wave * 1024),
            16, 0, 0);
    };

#define VM6 asm volatile("s_waitcnt vmcnt(6)" ::: "memory")
#define VM3 asm volatile("s_waitcnt vmcnt(3)" ::: "memory")
#define VM0 asm volatile("s_waitcnt vmcnt(0)" ::: "memory")
#define VMNONE ((void)0)

#define PHASE(C, SH, DOSTAGE, VMLINE)                                           \
    do {                                                                        \
        bf16x8 af[4], bq[4];                                                    \
        _Pragma("unroll")                                                       \
        for (int i_ = 0; i_ < 4; ++i_) {                                        \
            af[i_] = *(const bf16x8*)(smem + (C) * 24576 + aoff + i_ * 1024);   \
            bq[i_] = *(const bf16x8*)(smem + (C) * 24576 + boff + i_ * 1024);   \
        }                                                                       \
        if (DOSTAGE) stage((SH), ((C) + 3) & 3);                                \
        __builtin_amdgcn_s_barrier();                                           \
        asm volatile("s_waitcnt lgkmcnt(0)" ::: "memory");                      \
        __builtin_amdgcn_sched_barrier(0);                                      \
        __builtin_amdgcn_s_setprio(1);                                          \
        _Pragma("unroll")                                                       \
        for (int i_ = 0; i_ < 4; ++i_)                                          \
            _Pragma("unroll")                                                   \
            for (int j_ = 0; j_ < 4; ++j_)                                      \
                acc[i_][j_] = __builtin_amdgcn_mfma_f32_16x16x32_bf16(          \
                    af[i_], bq[j_], acc[i_][j_], 0, 0, 0);                      \
        __builtin_amdgcn_s_setprio(0);                                          \
        __builtin_amdgcn_sched_barrier(0);                                      \
        VMLINE;                                                                 \
        __builtin_amdgcn_s_barrier();                                           \
    } while (0)

    // prologue: halves 0,1,2 in flight (9 loads); retire half 0, keep 6 flying
    stage(0, 0); stage(1, 1); stage(2, 2);
    VM6;
    __builtin_amdgcn_s_barrier();

    // 136 halves total (K = 136*32). Main loop: halves 0..131, all stages
    // unconditional (max staged half = 134). Tail peels 132..135.
    for (int h4 = 0; h4 < 132; h4 += 4) {
        PHASE(0, h4 + 3, true, VM6);
        PHASE(1, h4 + 4, true, VM6);
        PHASE(2, h4 + 5, true, VM6);
        PHASE(3, h4 + 6, true, VM6);
    }
    PHASE(0, 135, true,  VM6);   // h=132: stage last half; retire 133
    PHASE(1, 0,   false, VM3);   // h=133: retire 134
    PHASE(2, 0,   false, VM0);   // h=134: retire 135
    PHASE(3, 0,   false, VMNONE);// h=135

#undef PHASE
#undef VM6
#undef VM3
#undef VM0
#undef VMNONE

    // ---- fused epilogue: four n-quarter passes ---------------------------
    // C/D layout: col = lane&15 (n), row = (lane>>4)*4 + reg (m)
    const int cw = lane & 15;
    const int rw = (lane >> 4) * 4;
    const int hl = tid & 15;                // h within pass
    const int rb = tid >> 4;                // 0..31

    for (int p = 0; p < 4; ++p) {
        __syncthreads();                    // prev readers done
        if ((wave & 3) == p) {              // 2 waves (wm=0,64) own quarter p
#pragma unroll
            for (int i = 0; i < 4; ++i)
#pragma unroll
                for (int jj = 0; jj < 4; ++jj)
#pragma unroll
                    for (int r = 0; r < 4; ++r)
                        sP[(wm + i * 16 + rw + r) * 76 + jj * 16 + cw] = acc[i][jj][r];
        }
        __syncthreads();                    // sP populated

        const int hg = (n0 >> 2) + p * 16 + hl;   // global hidden index
        const float b_i = bi[hg], b_f = bfv[hg], b_o = bo[hg], b_s = bs[hg];
#pragma unroll
        for (int k = 0; k < 4; ++k) {
            const int row = rb + 32 * k;          // 0..127
            float4 g = *(const float4*)(sP + row * 76 + hl * 4);
            const size_t oidx = (size_t)(m0 + row) * H_DIM + hg;
            float old = old_state[oidx];
            float ig = sigm_(g.x + b_i);
            float fg = sigm_(g.y + b_f);
            float og = sigm_(g.z + b_o);
            float ts = tanh_(g.w + b_s);
            out[oidx] = og * tanh_(fg * old + ig * ts);
        }
    }
}

// ---------------------------------------------------------------------------
extern "C" void kernel_launch(void* const* d_in, const int* in_sizes, int n_in,
                              void* d_out, int out_size, void* d_ws, size_t ws_size,
                              hipStream_t stream) {
    const float* x   = (const float*)d_in[0];
    const float* pt  = (const float*)d_in[1];
    const float* pl  = (const float*)d_in[2];
    const float* old = (const float*)d_in[3];
    const float* Wi  = (const float*)d_in[4];
    const float* bi  = (const float*)d_in[5];
    const float* Wf  = (const float*)d_in[6];
    const float* bf  = (const float*)d_in[7];
    const float* Wo  = (const float*)d_in[8];
    const float* bo  = (const float*)d_in[9];
    const float* Ws  = (const float*)d_in[10];
    const float* bs  = (const float*)d_in[11];
    float* out = (float*)d_out;

    char* ws = (char*)d_ws;
    unsigned short* Abf = (unsigned short*)(ws + A_OFF);
    unsigned short* Bbf = (unsigned short*)(ws + B_OFF);

    // 1) pack/convert: one block per destination row
    convert_kernel<<<M_DIM + N_DIM, 256, 0, stream>>>(x, pt, pl, Wi, Wf, Wo, Ws, Abf, Bbf);

    // 2) fused GEMM + gates, XCD-swizzled 1-D grid, 1 block/CU
    gemm_fused<<<256, 512, 0, stream>>>(Abf, Bbf, old, bi, bf, bo, bs, out);
}

// Round 2
// 231.112 us; speedup vs baseline: 1.0076x; 1.0027x over previous
//
#include <hip/hip_runtime.h>
#include <stdint.h>
#include <stddef.h>

#define M_DIM 2048
#define N_DIM 4096
#define K_DIM 4352
#define H_DIM 1024
#define X_DIM 2304

// workspace layout (bytes)
#define A_OFF 0u
#define B_OFF 17825792u                 // 2048*4352*2

typedef __bf16 bf16x8 __attribute__((ext_vector_type(8)));
typedef float f32x4 __attribute__((ext_vector_type(4)));

__device__ __forceinline__ unsigned short f32_to_bf16(float f) {
    unsigned u = __float_as_uint(f);
    u += 0x7FFFu + ((u >> 16) & 1u);     // round-to-nearest-even
    return (unsigned short)(u >> 16);
}

__device__ __forceinline__ float sigm_(float x) { return 1.f / (1.f + __expf(-x)); }
__device__ __forceinline__ float tanh_(float x) {
    x = fminf(15.f, fmaxf(-15.f, x));
    float e = __expf(2.f * x);
    return (e - 1.f) / (e + 1.f);
}

// ---------------------------------------------------------------------------
// Kernel 1 (unchanged): pack z -> A, W_all gate-interleaved -> B. bf16.
// ---------------------------------------------------------------------------
__global__ __launch_bounds__(256) void convert_kernel(
    const float* __restrict__ x, const float* __restrict__ pt,
    const float* __restrict__ pl,
    const float* __restrict__ Wi, const float* __restrict__ Wf,
    const float* __restrict__ Wo, const float* __restrict__ Ws,
    unsigned short* __restrict__ Abf, unsigned short* __restrict__ Bbf)
{
    const int row = blockIdx.x;                  // 0..6143
    const float* srow = nullptr;
    unsigned short* drow;
    if (row < M_DIM) {
        drow = Abf + (size_t)row * K_DIM;
    } else {
        int n = row - M_DIM;                      // 0..4095
        int g = n >> 10, h = n & 1023;
        const float* W = (g == 0) ? Wi : (g == 1) ? Wf : (g == 2) ? Wo : Ws;
        srow = W + (size_t)h * K_DIM;
        drow = Bbf + (size_t)(h * 4 + g) * K_DIM;
    }

    for (int c8 = threadIdx.x; c8 < K_DIM / 8; c8 += 256) {
        int col = c8 * 8;
        const float* s;
        if (row < M_DIM) {
            if (col < X_DIM)              s = x  + (size_t)row * X_DIM + col;
            else if (col < X_DIM + H_DIM) s = pt + (size_t)row * H_DIM + (col - X_DIM);
            else                          s = pl + (size_t)row * H_DIM + (col - X_DIM - H_DIM);
        } else {
            s = srow + col;
        }
        float4 v0 = ((const float4*)s)[0];
        float4 v1 = ((const float4*)s)[1];
        union { unsigned short h[8]; uint4 u; } r;
        r.h[0] = f32_to_bf16(v0.x); r.h[1] = f32_to_bf16(v0.y);
        r.h[2] = f32_to_bf16(v0.z); r.h[3] = f32_to_bf16(v0.w);
        r.h[4] = f32_to_bf16(v1.x); r.h[5] = f32_to_bf16(v1.y);
        r.h[6] = f32_to_bf16(v1.z); r.h[7] = f32_to_bf16(v1.w);
        *(uint4*)(drow + col) = r.u;
    }
}

// ---------------------------------------------------------------------------
// Kernel 2: fused GEMM + gates. Round-2 change: ONE barrier per phase.
// Ring of 4 half-buffers, stage DISTANCE 2 (body(p) stages half p+2), so the
// buffer being overwritten was last read 2 phases ago -> its reads completed
// before barrier(p-2), and the stage issues after barrier(p-1). Single
// rendezvous per phase; counted vmcnt(3) before the barrier (never 0 in the
// main loop); NO forced lgkmcnt(0) -- compiler emits partial lgkm waits so
// MFMAs start while later fragments land (LDS drain overlaps MFMA region).
// ---------------------------------------------------------------------------
__global__ __launch_bounds__(512, 2) void gemm_fused(
    const unsigned short* __restrict__ A,   // [M_DIM, K_DIM] bf16
    const unsigned short* __restrict__ B,   // [N_DIM, K_DIM] bf16, gate-interleaved
    const float* __restrict__ old_state,    // [2048, 1024]
    const float* __restrict__ bi, const float* __restrict__ bfv,
    const float* __restrict__ bo, const float* __restrict__ bs,
    float* __restrict__ out)                // [2048, 1024]
{
    // 4 half-buffers at c*24576: A half [128 rows][4 slots of 16B] = 8192 B,
    // B half [256 rows][4 slots] = 16384 B. sP (128*76*4 = 38912 B) aliases
    // buffers 0..1 in the epilogue.
    __shared__ __align__(16) char smem[98304];
    float* sP = (float*)smem;

    const int tid  = threadIdx.x;
    const int lane = tid & 63;
    const int wave = tid >> 6;              // 0..7
    const int wm = (wave >> 2) * 64;        // 0 | 64
    const int wn = (wave & 3) * 64;         // 0 | 64 | 128 | 192

    // XCD-aware decode: xcd owns 2 n-tiles (B panel ~4.5MB ~ L2)
    const int b   = blockIdx.x;             // 0..255
    const int xcd = b & 7;
    const int j   = b >> 3;                 // 0..31
    const int m0  = (j >> 1) * 128;         // 16 m-tiles
    const int n0  = (xcd * 2 + (j & 1)) * 256;  // 16 n-tiles

    // staging: linear LDS slot u*16 (u = i*512 + tid); row = u>>2, slot = u&3,
    // pre-swizzled source k-block kb = slot ^ ((row>>1)&3)
    const int srow_ = tid >> 2;             // 0..127
    const int kb_   = (tid & 3) ^ ((tid >> 3) & 3);
    const unsigned short* Asrc  = A + (size_t)(m0 + srow_)       * K_DIM + kb_ * 8;
    const unsigned short* Bsrc0 = B + (size_t)(n0 + srow_)       * K_DIM + kb_ * 8;
    const unsigned short* Bsrc1 = B + (size_t)(n0 + 128 + srow_) * K_DIM + kb_ * 8;

    // fragment reads: row = w? + i*16 + fr, k-block kb0 = lane>>4,
    // swizzled slot = kb0 ^ ((row>>1)&3) = kb0 ^ ((fr>>1)&3)
    const int fr  = lane & 15;
    const int kb0 = lane >> 4;
    const int swz = (kb0 ^ ((fr >> 1) & 3)) * 16;
    const int aoff = (wm + fr) * 64 + swz;
    const int boff = 8192 + (wn + fr) * 64 + swz;

    f32x4 acc[4][4];
#pragma unroll
    for (int i = 0; i < 4; ++i)
#pragma unroll
        for (int jj = 0; jj < 4; ++jj) acc[i][jj] = (f32x4){0.f, 0.f, 0.f, 0.f};

    // stage half-tile h (k in [h*32, h*32+32)) into ring buffer c: 3 loads/thread
    auto stage = [&](int h, int c) {
        const size_t koff = (size_t)h * 32;
        __builtin_amdgcn_global_load_lds(
            (const __attribute__((address_space(1))) unsigned*)(Asrc + koff),
            (__attribute__((address_space(3))) unsigned*)(smem + c * 24576 + wave * 1024),
            16, 0, 0);
        __builtin_amdgcn_global_load_lds(
            (const __attribute__((address_space(1))) unsigned*)(Bsrc0 + koff),
            (__attribute__((address_space(3))) unsigned*)(smem + c * 24576 + 8192 + wave * 1024),
            16, 0, 0);
        __builtin_amdgcn_global_load_lds(
            (const __attribute__((address_space(1))) unsigned*)(Bsrc1 + koff),
            (__attribute__((address_space(3))) unsigned*)(smem + c * 24576 + 16384 + wave * 1024),
            16, 0, 0);
    };

#define VM3 asm volatile("s_waitcnt vmcnt(3)" ::: "memory")
#define VM0 asm volatile("s_waitcnt vmcnt(0)" ::: "memory")
#define VMNONE ((void)0)

    // Phase p (buffer C = p&3): stage half p+2 into buf (p+2)&3; read C's
    // fragments; vmcnt(3) retires half p+1 (needed next phase); ONE barrier;
    // MFMA with compiler-scheduled partial lgkm waits.
#define PHASE(C, SH, DOSTAGE, VMLINE)                                           \
    do {                                                                        \
        if (DOSTAGE) stage((SH), ((C) + 2) & 3);                                \
        bf16x8 af[4], bq[4];                                                    \
        _Pragma("unroll")                                                       \
        for (int i_ = 0; i_ < 4; ++i_) {                                        \
            af[i_] = *(const bf16x8*)(smem + (C) * 24576 + aoff + i_ * 1024);   \
            bq[i_] = *(const bf16x8*)(smem + (C) * 24576 + boff + i_ * 1024);   \
        }                                                                       \
        VMLINE;                                                                 \
        __builtin_amdgcn_s_barrier();                                           \
        __builtin_amdgcn_s_setprio(1);                                          \
        _Pragma("unroll")                                                       \
        for (int i_ = 0; i_ < 4; ++i_)                                          \
            _Pragma("unroll")                                                   \
            for (int j_ = 0; j_ < 4; ++j_)                                      \
                acc[i_][j_] = __builtin_amdgcn_mfma_f32_16x16x32_bf16(          \
                    af[i_], bq[j_], acc[i_][j_], 0, 0, 0);                      \
        __builtin_amdgcn_s_setprio(0);                                          \
    } while (0)

    // prologue: halves 0,1 in flight (6 loads); vmcnt(3) retires half 0
    stage(0, 0); stage(1, 1);
    VM3;
    __builtin_amdgcn_s_barrier();

    // 136 halves total (K = 136*32). Phases 0..131 in the unrolled loop
    // (stage halves 2..133); peel 132..135.
    for (int h4 = 0; h4 < 132; h4 += 4) {
        PHASE(0, h4 + 2, true, VM3);
        PHASE(1, h4 + 3, true, VM3);
        PHASE(2, h4 + 4, true, VM3);
        PHASE(3, h4 + 5, true, VM3);
    }
    PHASE(0, 134, true,  VM3);   // phase 132: stage half 134; retire 133
    PHASE(1, 135, true,  VM3);   // phase 133: stage half 135; retire 134
    PHASE(2, 0,   false, VM0);   // phase 134: retire 135
    PHASE(3, 0,   false, VMNONE);// phase 135

#undef PHASE
#undef VM3
#undef VM0
#undef VMNONE

    // ---- fused epilogue: four n-quarter passes ---------------------------
    // C/D layout: col = lane&15 (n), row = (lane>>4)*4 + reg (m)
    const int cw = lane & 15;
    const int rw = (lane >> 4) * 4;
    const int hl = tid & 15;                // h within pass
    const int rb = tid >> 4;                // 0..31

    for (int p = 0; p < 4; ++p) {
        __syncthreads();                    // prev readers done
        if ((wave & 3) == p) {              // 2 waves (wm=0,64) own quarter p
#pragma unroll
            for (int i = 0; i < 4; ++i)
#pragma unroll
                for (int jj = 0; jj < 4; ++jj)
#pragma unroll
                    for (int r = 0; r < 4; ++r)
                        sP[(wm + i * 16 + rw + r) * 76 + jj * 16 + cw] = acc[i][jj][r];
        }
        __syncthreads();                    // sP populated

        const int hg = (n0 >> 2) + p * 16 + hl;   // global hidden index
        const float b_i = bi[hg], b_f = bfv[hg], b_o = bo[hg], b_s = bs[hg];
#pragma unroll
        for (int k = 0; k < 4; ++k) {
            const int row = rb + 32 * k;          // 0..127
            float4 g = *(const float4*)(sP + row * 76 + hl * 4);
            const size_t oidx = (size_t)(m0 + row) * H_DIM + hg;
            float old = old_state[oidx];
            float ig = sigm_(g.x + b_i);
            float fg = sigm_(g.y + b_f);
            float og = sigm_(g.z + b_o);
            float ts = tanh_(g.w + b_s);
            out[oidx] = og * tanh_(fg * old + ig * ts);
        }
    }
}

// ---------------------------------------------------------------------------
extern "C" void kernel_launch(void* const* d_in, const int* in_sizes, int n_in,
                              void* d_out, int out_size, void* d_ws, size_t ws_size,
                              hipStream_t stream) {
    const float* x   = (const float*)d_in[0];
    const float* pt  = (const float*)d_in[1];
    const float* pl  = (const float*)d_in[2];
    const float* old = (const float*)d_in[3];
    const float* Wi  = (const float*)d_in[4];
    const float* bi  = (const float*)d_in[5];
    const float* Wf  = (const float*)d_in[6];
    const float* bf  = (const float*)d_in[7];
    const float* Wo  = (const float*)d_in[8];
    const float* bo  = (const float*)d_in[9];
    const float* Ws  = (const float*)d_in[10];
    const float* bs  = (const float*)d_in[11];
    float* out = (float*)d_out;

    char* ws = (char*)d_ws;
    unsigned short* Abf = (unsigned short*)(ws + A_OFF);
    unsigned short* Bbf = (unsigned short*)(ws + B_OFF);

    // 1) pack/convert: one block per destination row
    convert_kernel<<<M_DIM + N_DIM, 256, 0, stream>>>(x, pt, pl, Wi, Wf, Wo, Ws, Abf, Bbf);

    // 2) fused GEMM + gates, XCD-swizzled 1-D grid, 1 block/CU
    gemm_fused<<<256, 512, 0, stream>>>(Abf, Bbf, old, bi, bf, bo, bs, out);
}